// Round 11
// baseline (130.429 us; speedup 1.0000x reference)
//
#include <hip/hip_runtime.h>
#include <hip/hip_bf16.h>
#include <math.h>

#define T_STEPS 64
#define BATCH   256
#define NX      512
#define NH      512

typedef short bf16x8 __attribute__((ext_vector_type(8)));
typedef float f32x4  __attribute__((ext_vector_type(4)));

// ---------------------------------------------------------------------------
// Kernel 1: P[r][h] = b1[h] + sum_k X[r][k] * W1[h][k]   (bf16 MFMA, f32 acc)
//   (unchanged — r10 register-prefetch version, verified)
// ---------------------------------------------------------------------------
__global__ __launch_bounds__(256) void gemm_bf16_kernel(
    const float* __restrict__ X,    // [16384][512]
    const float* __restrict__ W1,   // [512][512]
    const float* __restrict__ b1,   // [512]
    float* __restrict__ P)          // [16384][512]
{
    __shared__ unsigned short lds[16384];   // 32 KB: A = [0,8192), B = [8192,16384)

    const int tid  = threadIdx.x;
    const int lane = tid & 63;
    const int wave = tid >> 6;
    const int wm   = wave >> 1;
    const int wn   = wave & 1;
    const int rbase = blockIdx.x * 128;
    const int nbase = blockIdx.y * 128;

    int srow[4], skof[4];
#pragma unroll
    for (int i = 0; i < 4; ++i) {
        int g = tid + i * 256;
        int ks = g >> 9, ms = (g >> 6) & 7, l = g & 63;
        srow[i] = ms * 16 + (l & 15);
        skof[i] = ks * 32 + (l >> 4) * 8;
    }

    f32x4 acc[4][4] = {};
    float4 ra[4][2], rb[4][2];

#pragma unroll
    for (int i = 0; i < 4; ++i) {
        const float* sa = &X [(size_t)(rbase + srow[i]) * 512 + skof[i]];
        const float* sb = &W1[(size_t)(nbase + srow[i]) * 512 + skof[i]];
        ra[i][0] = *(const float4*)sa;  ra[i][1] = *(const float4*)(sa + 4);
        rb[i][0] = *(const float4*)sb;  rb[i][1] = *(const float4*)(sb + 4);
    }

    for (int kb = 0; kb < 512; kb += 64) {
#pragma unroll
        for (int i = 0; i < 4; ++i) {
            int g = tid + i * 256;
            union { __hip_bfloat162 q[4]; int4 pk; } ua, ub;
            ua.q[0] = __float22bfloat162_rn(make_float2(ra[i][0].x, ra[i][0].y));
            ua.q[1] = __float22bfloat162_rn(make_float2(ra[i][0].z, ra[i][0].w));
            ua.q[2] = __float22bfloat162_rn(make_float2(ra[i][1].x, ra[i][1].y));
            ua.q[3] = __float22bfloat162_rn(make_float2(ra[i][1].z, ra[i][1].w));
            ub.q[0] = __float22bfloat162_rn(make_float2(rb[i][0].x, rb[i][0].y));
            ub.q[1] = __float22bfloat162_rn(make_float2(rb[i][0].z, rb[i][0].w));
            ub.q[2] = __float22bfloat162_rn(make_float2(rb[i][1].x, rb[i][1].y));
            ub.q[3] = __float22bfloat162_rn(make_float2(rb[i][1].z, rb[i][1].w));
            *(int4*)&lds[g * 8]        = ua.pk;
            *(int4*)&lds[8192 + g * 8] = ub.pk;
        }
        __syncthreads();

        if (kb < 448) {
#pragma unroll
            for (int i = 0; i < 4; ++i) {
                const float* sa = &X [(size_t)(rbase + srow[i]) * 512 + kb + 64 + skof[i]];
                const float* sb = &W1[(size_t)(nbase + srow[i]) * 512 + kb + 64 + skof[i]];
                ra[i][0] = *(const float4*)sa;  ra[i][1] = *(const float4*)(sa + 4);
                rb[i][0] = *(const float4*)sb;  rb[i][1] = *(const float4*)(sb + 4);
            }
        }

#pragma unroll
        for (int ks = 0; ks < 2; ++ks) {
            bf16x8 afr[4], bfr[4];
#pragma unroll
            for (int mf = 0; mf < 4; ++mf)
                afr[mf] = *(const bf16x8*)&lds[((ks * 8 + wm * 4 + mf) * 64 + lane) * 8];
#pragma unroll
            for (int nf = 0; nf < 4; ++nf)
                bfr[nf] = *(const bf16x8*)&lds[8192 + ((ks * 8 + wn * 4 + nf) * 64 + lane) * 8];
#pragma unroll
            for (int mf = 0; mf < 4; ++mf)
#pragma unroll
                for (int nf = 0; nf < 4; ++nf)
                    acc[mf][nf] = __builtin_amdgcn_mfma_f32_16x16x32_bf16(
                        afr[mf], bfr[nf], acc[mf][nf], 0, 0, 0);
        }
        __syncthreads();
    }

    float bc[4];
#pragma unroll
    for (int nf = 0; nf < 4; ++nf)
        bc[nf] = b1[nbase + wn * 64 + nf * 16 + (lane & 15)];
#pragma unroll
    for (int mf = 0; mf < 4; ++mf) {
#pragma unroll
        for (int nf = 0; nf < 4; ++nf) {
#pragma unroll
            for (int r = 0; r < 4; ++r) {
                int m = rbase + wm * 64 + mf * 16 + ((lane >> 4) << 2) + r;
                int n = nbase + wn * 64 + nf * 16 + (lane & 15);
                P[(size_t)m * 512 + n] = acc[mf][nf][r] + bc[nf];
            }
        }
    }
}

// ---------------------------------------------------------------------------
// Kernel 2: per-batch Gram via MFMA (unchanged — verified rounds 8-10)
// ---------------------------------------------------------------------------
__global__ __launch_bounds__(256) void gram_kernel(
    const float* __restrict__ X,    // [T][B][NX]
    float* __restrict__ Gt)         // [B][64][64]
{
    const int b    = blockIdx.x;
    const int tid  = threadIdx.x;
    const int lane = tid & 63;
    const int w    = tid >> 6;

    __shared__ unsigned short xs[4096 * 8];   // 64 KB, fragment order

#pragma unroll
    for (int i = 0; i < 16; ++i) {
        int g   = tid + i * 256;
        int ks  = g >> 8;
        int ms  = (g >> 6) & 3;
        int l   = g & 63;
        int row = ms * 16 + (l & 15);
        int k   = ks * 32 + (l >> 4) * 8;
        const float* src = &X[(size_t)row * (BATCH * NX) + (size_t)b * NX + k];
        float4 v0 = *(const float4*)src;
        float4 v1 = *(const float4*)(src + 4);
        union { __hip_bfloat162 q[4]; int4 pk; } u;
        u.q[0] = __float22bfloat162_rn(make_float2(v0.x, v0.y));
        u.q[1] = __float22bfloat162_rn(make_float2(v0.z, v0.w));
        u.q[2] = __float22bfloat162_rn(make_float2(v1.x, v1.y));
        u.q[3] = __float22bfloat162_rn(make_float2(v1.z, v1.w));
        *(int4*)&xs[g * 8] = u.pk;
    }
    __syncthreads();

    f32x4 acc[4] = {};
#pragma unroll
    for (int ks = 0; ks < 16; ++ks) {
        bf16x8 afr = *(const bf16x8*)&xs[((ks * 4 + w) * 64 + lane) * 8];
#pragma unroll
        for (int nf = 0; nf < 4; ++nf) {
            bf16x8 bfr = *(const bf16x8*)&xs[((ks * 4 + nf) * 64 + lane) * 8];
            acc[nf] = __builtin_amdgcn_mfma_f32_16x16x32_bf16(afr, bfr, acc[nf], 0, 0, 0);
        }
    }

#pragma unroll
    for (int nf = 0; nf < 4; ++nf) {
#pragma unroll
        for (int r = 0; r < 4; ++r) {
            int mrow = w * 16 + ((lane >> 4) << 2) + r;
            int ncol = nf * 16 + (lane & 15);
            Gt[((size_t)b * 64 + mrow) * 64 + ncol] = acc[nf][r];
        }
    }
}

// ---------------------------------------------------------------------------
// 64-lane sum via DPP; result valid in lane 63. (HW-verified rounds 4-10)
// ---------------------------------------------------------------------------
__device__ __forceinline__ float dpp_sum64(float v) {
    v += __int_as_float(__builtin_amdgcn_update_dpp(0, __float_as_int(v), 0x111, 0xf, 0xf, true)); // row_shr:1
    v += __int_as_float(__builtin_amdgcn_update_dpp(0, __float_as_int(v), 0x112, 0xf, 0xf, true)); // row_shr:2
    v += __int_as_float(__builtin_amdgcn_update_dpp(0, __float_as_int(v), 0x114, 0xf, 0xf, true)); // row_shr:4
    v += __int_as_float(__builtin_amdgcn_update_dpp(0, __float_as_int(v), 0x118, 0xf, 0xf, true)); // row_shr:8
    v += __int_as_float(__builtin_amdgcn_update_dpp(0, __float_as_int(v), 0x142, 0xf, 0xf, true)); // row_bcast:15
    v += __int_as_float(__builtin_amdgcn_update_dpp(0, __float_as_int(v), 0x143, 0xf, 0xf, true)); // row_bcast:31
    return v;
}

__device__ __forceinline__ float readlane63(float v) {
    return __int_as_float(__builtin_amdgcn_readlane(__float_as_int(v), 63));
}

// ---------------------------------------------------------------------------
// Kernel 3: scan v4 — ONE WAVE PER BATCH, ZERO BARRIERS.
//   The 512-thread/8-wave structure was stuck at ~1860 cy/step (r7/r9/r10 all
//   49-51 us): the per-step cross-wave reduce + 8-wave barrier IS the cost.
//   Now: 64 threads (1 wave) per batch, lane owns 8 h-units, h = lane + 64*hi
//   (stride-1 LDS/global access per hi -> conflict-free, coalesced).
//   * a2 all-reduce is pure in-wave: 16-fmaf dot + DPP + readlane -> SGPR.
//     NO __syncthreads in the whole kernel (intra-wave LDS ordering only).
//   * chunk=8: hcur[8][8] + macc[8][8] registers, static indices (rule #20);
//     macc dies as hcur fills -> peak VGPR manageable.
//   * history in LDS Hsl[64][512] f32 (128 KB -> 1 block/CU, whole LDS ours);
//     C[8][64] per chunk + lam_pow table, built by the wave, no sync needed.
//   * P (2-step) and chain-coeff rows (1-step) prefetched ahead.
// ---------------------------------------------------------------------------
__global__ __launch_bounds__(64, 1) void scan_kernel(
    const float* __restrict__ P,    // [T][B][NH]  (== outH, aliased)
    const float* __restrict__ Gt,   // [B][64][64]
    const float* __restrict__ w2,   // [NH][2]
    const float* __restrict__ b2,   // [2]
    const float* __restrict__ w21,  // [NH][2]
    const float* __restrict__ lamp,
    const float* __restrict__ etap,
    float* __restrict__ outH,       // [T][B][NH]
    float* __restrict__ outY)       // [T][B][2]
{
    const int b    = blockIdx.x;
    const int lane = threadIdx.x;   // 0..63

    __shared__ float Hsl[64][512];  // 128 KB history
    __shared__ float C[8][64];      // current chunk's coeff rows
    __shared__ float lam_pow[64];

    const float eta = etap[0];
    const float lam = fminf(lamp[0], 1.0f);
    lam_pow[lane] = exp2f((float)lane * log2f(lam));   // lane 0 -> 1.0

    float2 w2v[8], w21v[8];
#pragma unroll
    for (int hi = 0; hi < 8; ++hi) {
        int h = lane + 64 * hi;
        w2v[hi]  = *(const float2*)&w2[2 * h];
        w21v[hi] = *(const float2*)&w21[2 * h];
    }
    const float b20 = b2[0], b21 = b2[1];
    const float* gb  = Gt + (size_t)b * 4096;
    const float* Pb  = P + (size_t)b * NH;
    float*       oHb = outH + (size_t)b * NH;

    // 2-deep P prefetch: pvn[t&1] holds P[t] for the next two steps
    float pvn[2][8];
#pragma unroll
    for (int hi = 0; hi < 8; ++hi) {
        pvn[0][hi] = Pb[(size_t)0 * (BATCH * NH) + lane + 64 * hi];
        pvn[1][hi] = Pb[(size_t)1 * (BATCH * NH) + lane + 64 * hi];
    }

    float a2x = 0.f, a2y = 0.f;    // uniform (readlane'd) - lives in SGPR

#pragma unroll 1
    for (int c = 0; c < 8; ++c) {
        const int t0 = c * 8;

        // ---- build C rows for this chunk (one entry per lane per row) ----
#pragma unroll
        for (int i = 0; i < 8; ++i) {
            int t = t0 + i;
            float cv = 0.f;
            if (lane < t) cv = eta * lam_pow[t - 1 - lane] * gb[t * 64 + lane];
            C[i][lane] = cv;
        }

        // ---- past-chunk history matmul into registers -------------------
        float macc[8][8] = {};
        for (int s = 0; s < t0; ++s) {        // runtime s; macc indices static
            float hsv[8];
#pragma unroll
            for (int hi = 0; hi < 8; ++hi)
                hsv[hi] = Hsl[s][lane + 64 * hi];
            float cc[8];
#pragma unroll
            for (int tt = 0; tt < 8; ++tt)
                cc[tt] = C[tt][s];
#pragma unroll
            for (int tt = 0; tt < 8; ++tt)
#pragma unroll
                for (int hi = 0; hi < 8; ++hi)
                    macc[tt][hi] = fmaf(cc[tt], hsv[hi], macc[tt][hi]);
        }

        // ---- 8 sequential steps, all in-wave ----------------------------
        float hcur[8][8];
        float cfr[8] = {};          // chain coeffs C[tt][t0..t0+7] for current tt
#pragma unroll
        for (int tt = 0; tt < 8; ++tt) {
            const int t = t0 + tt;

            float a1[8], hv[8];
            float p0 = 0.f, p1 = 0.f;
#pragma unroll
            for (int hi = 0; hi < 8; ++hi) {
                float a = pvn[tt & 1][hi] + w21v[hi].x * a2x + w21v[hi].y * a2y
                        + macc[tt][hi];
#pragma unroll
                for (int j = 0; j < tt; ++j)
                    a = fmaf(cfr[j], hcur[j][hi], a);
                a1[hi] = a;
            }
#pragma unroll
            for (int hi = 0; hi < 8; ++hi) {
                hv[hi] = 1.0f / (1.0f + __expf(-a1[hi]));
                hcur[tt][hi] = hv[hi];
                p0 = fmaf(hv[hi], w2v[hi].x, p0);
                p1 = fmaf(hv[hi], w2v[hi].y, p1);
            }

            // history + output stores (fire-and-forget; no barrier ever waits)
#pragma unroll
            for (int hi = 0; hi < 8; ++hi) {
                Hsl[t][lane + 64 * hi] = hv[hi];
                oHb[(size_t)t * (BATCH * NH) + lane + 64 * hi] = hv[hi];
            }

            // prefetch P[t+2] into the slot just consumed
            if (t < 62) {
#pragma unroll
                for (int hi = 0; hi < 8; ++hi)
                    pvn[tt & 1][hi] = Pb[(size_t)(t + 2) * (BATCH * NH) + lane + 64 * hi];
            }

            // prefetch next step's chain-coeff row (uniform LDS broadcast)
            if (tt < 7) {
                float4 cA = *(const float4*)&C[tt + 1][t0];
                float4 cB = *(const float4*)&C[tt + 1][t0 + 4];
                cfr[0] = cA.x; cfr[1] = cA.y; cfr[2] = cA.z; cfr[3] = cA.w;
                cfr[4] = cB.x; cfr[5] = cB.y; cfr[6] = cB.z; cfr[7] = cB.w;
            }

            // in-wave all-reduce -> uniform a2
            p0 = dpp_sum64(p0);
            p1 = dpp_sum64(p1);
            float s0 = b20 + readlane63(p0);
            float s1 = b21 + readlane63(p1);
            a2x = s0; a2y = s1;
            if (lane == 0) {
                outY[((size_t)t * BATCH + b) * 2 + 0] = 1.0f / (1.0f + __expf(-s0));
                outY[((size_t)t * BATCH + b) * 2 + 1] = 1.0f / (1.0f + __expf(-s1));
            }
        }
    }
}

// ---------------------------------------------------------------------------
extern "C" void kernel_launch(void* const* d_in, const int* in_sizes, int n_in,
                              void* d_out, int out_size, void* d_ws, size_t ws_size,
                              hipStream_t stream) {
    const float* x   = (const float*)d_in[0];
    const float* w1  = (const float*)d_in[1];
    const float* b1  = (const float*)d_in[2];
    const float* w2  = (const float*)d_in[3];
    const float* b2  = (const float*)d_in[4];
    const float* w21 = (const float*)d_in[5];
    const float* lam = (const float*)d_in[6];
    const float* eta = (const float*)d_in[7];

    float* outH = (float*)d_out;                       // [64*256*512], doubles as P
    float* outY = outH + (size_t)T_STEPS * BATCH * NH; // [64*256*2]
    float* Gt   = (float*)d_ws;                        // [256*64*64] = 4 MB

    gemm_bf16_kernel<<<dim3(128, 4), 256, 0, stream>>>(x, w1, b1, outH);
    gram_kernel<<<256, 256, 0, stream>>>(x, Gt);
    scan_kernel<<<256, 64, 0, stream>>>(outH, Gt, w2, b2, w21, lam, eta, outH, outY);
}

// Round 12
// 91.224 us; speedup vs baseline: 1.4298x; 1.4298x over previous
//
#include <hip/hip_runtime.h>
#include <hip/hip_bf16.h>
#include <math.h>

#define T_STEPS 64
#define BATCH   256
#define NX      512
#define NH      512

typedef short bf16x8 __attribute__((ext_vector_type(8)));
typedef float f32x4  __attribute__((ext_vector_type(4)));

// ---------------------------------------------------------------------------
// Kernel 1: P[r][h] = b1[h] + sum_k X[r][k] * W1[h][k]   (bf16 MFMA, f32 acc)
//   (unchanged — r10 register-prefetch version, verified)
// ---------------------------------------------------------------------------
__global__ __launch_bounds__(256) void gemm_bf16_kernel(
    const float* __restrict__ X,    // [16384][512]
    const float* __restrict__ W1,   // [512][512]
    const float* __restrict__ b1,   // [512]
    float* __restrict__ P)          // [16384][512]
{
    __shared__ unsigned short lds[16384];   // 32 KB: A = [0,8192), B = [8192,16384)

    const int tid  = threadIdx.x;
    const int lane = tid & 63;
    const int wave = tid >> 6;
    const int wm   = wave >> 1;
    const int wn   = wave & 1;
    const int rbase = blockIdx.x * 128;
    const int nbase = blockIdx.y * 128;

    int srow[4], skof[4];
#pragma unroll
    for (int i = 0; i < 4; ++i) {
        int g = tid + i * 256;
        int ks = g >> 9, ms = (g >> 6) & 7, l = g & 63;
        srow[i] = ms * 16 + (l & 15);
        skof[i] = ks * 32 + (l >> 4) * 8;
    }

    f32x4 acc[4][4] = {};
    float4 ra[4][2], rb[4][2];

#pragma unroll
    for (int i = 0; i < 4; ++i) {
        const float* sa = &X [(size_t)(rbase + srow[i]) * 512 + skof[i]];
        const float* sb = &W1[(size_t)(nbase + srow[i]) * 512 + skof[i]];
        ra[i][0] = *(const float4*)sa;  ra[i][1] = *(const float4*)(sa + 4);
        rb[i][0] = *(const float4*)sb;  rb[i][1] = *(const float4*)(sb + 4);
    }

    for (int kb = 0; kb < 512; kb += 64) {
#pragma unroll
        for (int i = 0; i < 4; ++i) {
            int g = tid + i * 256;
            union { __hip_bfloat162 q[4]; int4 pk; } ua, ub;
            ua.q[0] = __float22bfloat162_rn(make_float2(ra[i][0].x, ra[i][0].y));
            ua.q[1] = __float22bfloat162_rn(make_float2(ra[i][0].z, ra[i][0].w));
            ua.q[2] = __float22bfloat162_rn(make_float2(ra[i][1].x, ra[i][1].y));
            ua.q[3] = __float22bfloat162_rn(make_float2(ra[i][1].z, ra[i][1].w));
            ub.q[0] = __float22bfloat162_rn(make_float2(rb[i][0].x, rb[i][0].y));
            ub.q[1] = __float22bfloat162_rn(make_float2(rb[i][0].z, rb[i][0].w));
            ub.q[2] = __float22bfloat162_rn(make_float2(rb[i][1].x, rb[i][1].y));
            ub.q[3] = __float22bfloat162_rn(make_float2(rb[i][1].z, rb[i][1].w));
            *(int4*)&lds[g * 8]        = ua.pk;
            *(int4*)&lds[8192 + g * 8] = ub.pk;
        }
        __syncthreads();

        if (kb < 448) {
#pragma unroll
            for (int i = 0; i < 4; ++i) {
                const float* sa = &X [(size_t)(rbase + srow[i]) * 512 + kb + 64 + skof[i]];
                const float* sb = &W1[(size_t)(nbase + srow[i]) * 512 + kb + 64 + skof[i]];
                ra[i][0] = *(const float4*)sa;  ra[i][1] = *(const float4*)(sa + 4);
                rb[i][0] = *(const float4*)sb;  rb[i][1] = *(const float4*)(sb + 4);
            }
        }

#pragma unroll
        for (int ks = 0; ks < 2; ++ks) {
            bf16x8 afr[4], bfr[4];
#pragma unroll
            for (int mf = 0; mf < 4; ++mf)
                afr[mf] = *(const bf16x8*)&lds[((ks * 8 + wm * 4 + mf) * 64 + lane) * 8];
#pragma unroll
            for (int nf = 0; nf < 4; ++nf)
                bfr[nf] = *(const bf16x8*)&lds[8192 + ((ks * 8 + wn * 4 + nf) * 64 + lane) * 8];
#pragma unroll
            for (int mf = 0; mf < 4; ++mf)
#pragma unroll
                for (int nf = 0; nf < 4; ++nf)
                    acc[mf][nf] = __builtin_amdgcn_mfma_f32_16x16x32_bf16(
                        afr[mf], bfr[nf], acc[mf][nf], 0, 0, 0);
        }
        __syncthreads();
    }

    float bc[4];
#pragma unroll
    for (int nf = 0; nf < 4; ++nf)
        bc[nf] = b1[nbase + wn * 64 + nf * 16 + (lane & 15)];
#pragma unroll
    for (int mf = 0; mf < 4; ++mf) {
#pragma unroll
        for (int nf = 0; nf < 4; ++nf) {
#pragma unroll
            for (int r = 0; r < 4; ++r) {
                int m = rbase + wm * 64 + mf * 16 + ((lane >> 4) << 2) + r;
                int n = nbase + wn * 64 + nf * 16 + (lane & 15);
                P[(size_t)m * 512 + n] = acc[mf][nf][r] + bc[nf];
            }
        }
    }
}

// ---------------------------------------------------------------------------
// Kernel 2: per-batch Gram via MFMA (unchanged — verified rounds 8-11)
// ---------------------------------------------------------------------------
__global__ __launch_bounds__(256) void gram_kernel(
    const float* __restrict__ X,    // [T][B][NX]
    float* __restrict__ Gt)         // [B][64][64]
{
    const int b    = blockIdx.x;
    const int tid  = threadIdx.x;
    const int lane = tid & 63;
    const int w    = tid >> 6;

    __shared__ unsigned short xs[4096 * 8];   // 64 KB, fragment order

#pragma unroll
    for (int i = 0; i < 16; ++i) {
        int g   = tid + i * 256;
        int ks  = g >> 8;
        int ms  = (g >> 6) & 3;
        int l   = g & 63;
        int row = ms * 16 + (l & 15);
        int k   = ks * 32 + (l >> 4) * 8;
        const float* src = &X[(size_t)row * (BATCH * NX) + (size_t)b * NX + k];
        float4 v0 = *(const float4*)src;
        float4 v1 = *(const float4*)(src + 4);
        union { __hip_bfloat162 q[4]; int4 pk; } u;
        u.q[0] = __float22bfloat162_rn(make_float2(v0.x, v0.y));
        u.q[1] = __float22bfloat162_rn(make_float2(v0.z, v0.w));
        u.q[2] = __float22bfloat162_rn(make_float2(v1.x, v1.y));
        u.q[3] = __float22bfloat162_rn(make_float2(v1.z, v1.w));
        *(int4*)&xs[g * 8] = u.pk;
    }
    __syncthreads();

    f32x4 acc[4] = {};
#pragma unroll
    for (int ks = 0; ks < 16; ++ks) {
        bf16x8 afr = *(const bf16x8*)&xs[((ks * 4 + w) * 64 + lane) * 8];
#pragma unroll
        for (int nf = 0; nf < 4; ++nf) {
            bf16x8 bfr = *(const bf16x8*)&xs[((ks * 4 + nf) * 64 + lane) * 8];
            acc[nf] = __builtin_amdgcn_mfma_f32_16x16x32_bf16(afr, bfr, acc[nf], 0, 0, 0);
        }
    }

#pragma unroll
    for (int nf = 0; nf < 4; ++nf) {
#pragma unroll
        for (int r = 0; r < 4; ++r) {
            int mrow = w * 16 + ((lane >> 4) << 2) + r;
            int ncol = nf * 16 + (lane & 15);
            Gt[((size_t)b * 64 + mrow) * 64 + ncol] = acc[nf][r];
        }
    }
}

// ---------------------------------------------------------------------------
// 64-lane sum via DPP; result valid in lane 63. (HW-verified rounds 4-11)
// ---------------------------------------------------------------------------
__device__ __forceinline__ float dpp_sum64(float v) {
    v += __int_as_float(__builtin_amdgcn_update_dpp(0, __float_as_int(v), 0x111, 0xf, 0xf, true)); // row_shr:1
    v += __int_as_float(__builtin_amdgcn_update_dpp(0, __float_as_int(v), 0x112, 0xf, 0xf, true)); // row_shr:2
    v += __int_as_float(__builtin_amdgcn_update_dpp(0, __float_as_int(v), 0x114, 0xf, 0xf, true)); // row_shr:4
    v += __int_as_float(__builtin_amdgcn_update_dpp(0, __float_as_int(v), 0x118, 0xf, 0xf, true)); // row_shr:8
    v += __int_as_float(__builtin_amdgcn_update_dpp(0, __float_as_int(v), 0x142, 0xf, 0xf, true)); // row_bcast:15
    v += __int_as_float(__builtin_amdgcn_update_dpp(0, __float_as_int(v), 0x143, 0xf, 0xf, true)); // row_bcast:31
    return v;
}

// ---------------------------------------------------------------------------
// Kernel 3: scan v5 — r7 skeleton (8 waves, 512 thr, 1 barrier/step) with the
// a2 critical path shortened:
//   * phase D precomputes partial_{t+1} = pvreg + macc + sum_{j<=tt} C*hcur
//     BEFORE the barrier -> post-barrier chain is only
//     red read -> tree -> 2 fmaf -> sigmoid -> dot -> DPP -> red write.
//   * outY[t] written at step t+1 (where a2_{t+1} is formed); tail writes t=63.
//     a2_0 = 0 exactly as reference.
//   * macc burst reads C via float4 (s tiled by 4): 20 LDS ops / 4 history
//     steps instead of 68 (wave-uniform scalar reads were an LDS-issue tax).
//   Parity: step t reads red[(t-1)&1], writes red[t&1] -> no WAR across waves.
// ---------------------------------------------------------------------------
__global__ __launch_bounds__(512, 1) void scan_kernel(
    const float* __restrict__ P,    // [T][B][NH]  (== outH, aliased)
    const float* __restrict__ Gt,   // [B][64][64]
    const float* __restrict__ w2,   // [NH][2]
    const float* __restrict__ b2,   // [2]
    const float* __restrict__ w21,  // [NH][2]
    const float* __restrict__ lamp,
    const float* __restrict__ etap,
    float* __restrict__ outH,       // [T][B][NH]
    float* __restrict__ outY)       // [T][B][2]
{
    const int b = blockIdx.x;
    const int h = threadIdx.x;

    __shared__ float Hs[64][512];   // 128 KB history; col h private to thread h
    __shared__ float C[16][64];     // per-chunk coefficient matrix
    __shared__ float lam_pow[64];
    __shared__ float red[2][16];

    const float eta = etap[0];
    const float lam = fminf(lamp[0], 1.0f);
    const float2 w21v = *(const float2*)&w21[2 * h];
    const float2 w2v  = *(const float2*)&w2[2 * h];
    const float b20 = b2[0], b21 = b2[1];
    const float* gb  = Gt + (size_t)b * 4096;
    const float* Pb  = P + (size_t)b * NH + h;
    float*       oHb = outH + (size_t)b * NH + h;

    if (h < 64)
        lam_pow[h] = (h == 0) ? 1.0f : exp2f((float)h * log2f(lam));
    __syncthreads();   // order lam_pow writes before chunk-0 C-build reads

#pragma unroll 1
    for (int c = 0; c < 4; ++c) {
        const int t0 = c * 16;

        // ---- build C cooperatively: 1024 entries, 2 per thread ----------
        // (all C reads of the previous chunk precede its last per-step barrier)
#pragma unroll
        for (int e = h; e < 1024; e += 512) {
            int tt = e >> 6, s = e & 63;
            int t  = t0 + tt;
            float cv = 0.f;
            if (s < t) cv = eta * lam_pow[t - 1 - s] * gb[t * 64 + s];
            C[tt][s] = cv;
        }

        // ---- preload chunk's P (covered by C-build + macc burst) --------
        float pvreg[16];
#pragma unroll
        for (int tt = 0; tt < 16; ++tt)
            pvreg[tt] = Pb[(size_t)(t0 + tt) * (BATCH * NH)];

        __syncthreads();   // C visible; also orders prev chunk's last red write

        // ---- past-chunk history matmul (float4 C reads, s tiled by 4) ---
        float macc[16] = {};
        for (int s4 = 0; s4 < t0; s4 += 4) {
            float hsv0 = Hs[s4 + 0][h];
            float hsv1 = Hs[s4 + 1][h];
            float hsv2 = Hs[s4 + 2][h];
            float hsv3 = Hs[s4 + 3][h];
#pragma unroll
            for (int tt = 0; tt < 16; ++tt) {
                float4 cf = *(const float4*)&C[tt][s4];
                macc[tt] = fmaf(cf.x, hsv0, macc[tt]);
                macc[tt] = fmaf(cf.y, hsv1, macc[tt]);
                macc[tt] = fmaf(cf.z, hsv2, macc[tt]);
                macc[tt] = fmaf(cf.w, hsv3, macc[tt]);
            }
        }

        // ---- 16 sequential steps ----------------------------------------
        float hcur[16];
        float partial = pvreg[0] + macc[0];
#pragma unroll
        for (int tt = 0; tt < 16; ++tt) {
            const int t = t0 + tt;

            // phase A: form a2_t from step t-1's reduce (post-barrier chain)
            float a2x, a2y;
            if (t == 0) {
                a2x = 0.f; a2y = 0.f;       // reference: a2 carry init = zeros
            } else {
                const int pr = (t - 1) & 1;
                float4 r0 = *(const float4*)&red[pr][0];
                float4 r1 = *(const float4*)&red[pr][4];
                float4 r2 = *(const float4*)&red[pr][8];
                float4 r3 = *(const float4*)&red[pr][12];
                float s0 = b20 + ((r0.x + r0.z) + (r1.x + r1.z)) + ((r2.x + r2.z) + (r3.x + r3.z));
                float s1 = b21 + ((r0.y + r0.w) + (r1.y + r1.w)) + ((r2.y + r2.w) + (r3.y + r3.w));
                a2x = s0; a2y = s1;
                if (h == 0) {
                    outY[((size_t)(t - 1) * BATCH + b) * 2 + 0] = 1.0f / (1.0f + __expf(-s0));
                    outY[((size_t)(t - 1) * BATCH + b) * 2 + 1] = 1.0f / (1.0f + __expf(-s1));
                }
            }

            // phase B: h_t
            float a1 = partial + w21v.x * a2x + w21v.y * a2y;
            float hv = 1.0f / (1.0f + __expf(-a1));
            hcur[tt] = hv;
            Hs[t][h] = hv;
            oHb[(size_t)t * (BATCH * NH)] = hv;

            // phase C: reduce h_t . w2
            float p0 = dpp_sum64(hv * w2v.x);
            float p1 = dpp_sum64(hv * w2v.y);
            if ((h & 63) == 63) {
                red[t & 1][(h >> 6) * 2]     = p0;
                red[t & 1][(h >> 6) * 2 + 1] = p1;
            }

            // phase D (off the a2 chain): next step's partial
            if (tt < 15) {
                partial = pvreg[tt + 1] + macc[tt + 1];
#pragma unroll
                for (int j = 0; j <= tt; ++j)
                    partial = fmaf(C[tt + 1][t0 + j], hcur[j], partial);
            }

            __syncthreads();
        }
    }

    // ---- tail: outY[63] from the final reduce (ordered by last barrier) --
    {
        float4 r0 = *(const float4*)&red[63 & 1][0];
        float4 r1 = *(const float4*)&red[63 & 1][4];
        float4 r2 = *(const float4*)&red[63 & 1][8];
        float4 r3 = *(const float4*)&red[63 & 1][12];
        float s0 = b20 + ((r0.x + r0.z) + (r1.x + r1.z)) + ((r2.x + r2.z) + (r3.x + r3.z));
        float s1 = b21 + ((r0.y + r0.w) + (r1.y + r1.w)) + ((r2.y + r2.w) + (r3.y + r3.w));
        if (h == 0) {
            outY[((size_t)63 * BATCH + b) * 2 + 0] = 1.0f / (1.0f + __expf(-s0));
            outY[((size_t)63 * BATCH + b) * 2 + 1] = 1.0f / (1.0f + __expf(-s1));
        }
    }
}

// ---------------------------------------------------------------------------
extern "C" void kernel_launch(void* const* d_in, const int* in_sizes, int n_in,
                              void* d_out, int out_size, void* d_ws, size_t ws_size,
                              hipStream_t stream) {
    const float* x   = (const float*)d_in[0];
    const float* w1  = (const float*)d_in[1];
    const float* b1  = (const float*)d_in[2];
    const float* w2  = (const float*)d_in[3];
    const float* b2  = (const float*)d_in[4];
    const float* w21 = (const float*)d_in[5];
    const float* lam = (const float*)d_in[6];
    const float* eta = (const float*)d_in[7];

    float* outH = (float*)d_out;                       // [64*256*512], doubles as P
    float* outY = outH + (size_t)T_STEPS * BATCH * NH; // [64*256*2]
    float* Gt   = (float*)d_ws;                        // [256*64*64] = 4 MB

    gemm_bf16_kernel<<<dim3(128, 4), 256, 0, stream>>>(x, w1, b1, outH);
    gram_kernel<<<256, 256, 0, stream>>>(x, Gt);
    scan_kernel<<<256, 512, 0, stream>>>(outH, Gt, w2, b2, w21, lam, eta, outH, outY);
}

// Round 13
// 89.402 us; speedup vs baseline: 1.4589x; 1.0204x over previous
//
#include <hip/hip_runtime.h>
#include <hip/hip_bf16.h>
#include <math.h>

#define T_STEPS 64
#define BATCH   256
#define NX      512
#define NH      512

typedef short bf16x8 __attribute__((ext_vector_type(8)));
typedef float f32x4  __attribute__((ext_vector_type(4)));

// ---------------------------------------------------------------------------
// Kernel 1: P[r][h] = b1[h] + sum_k X[r][k] * W1[h][k]   (bf16 MFMA, f32 acc)
//   v3: double-buffered LDS + ONE raw barrier per K-iter.
//   * lds[2][16K]: MFMA reads buf p while cvt+ds_write stages tile kb+1 into
//     buf p^1 -> staging overlaps compute; write-vs-read separated by one
//     barrier (iter i's writes to p^1 vs iter i-1's reads of p^1).
//   * barrier = asm "s_waitcnt lgkmcnt(0); s_barrier" (LDS visibility only,
//     NO vmcnt drain) -> prefetched global loads issued mid-iter stay in
//     flight across the barrier and drain at the consuming cvt's natural
//     vmcnt wait one iteration later (full-iter latency cover).
//   Fragment layout / MFMA / epilogue unchanged (verified r3-r12).
// ---------------------------------------------------------------------------
__global__ __launch_bounds__(256) void gemm_bf16_kernel(
    const float* __restrict__ X,    // [16384][512]
    const float* __restrict__ W1,   // [512][512]
    const float* __restrict__ b1,   // [512]
    float* __restrict__ P)          // [16384][512]
{
    __shared__ unsigned short lds[2][16384];  // 64 KB: [buf][A 8192 | B 8192]

    const int tid  = threadIdx.x;
    const int lane = tid & 63;
    const int wave = tid >> 6;
    const int wm   = wave >> 1;
    const int wn   = wave & 1;
    const int rbase = blockIdx.x * 128;
    const int nbase = blockIdx.y * 128;

    int srow[4], skof[4];
#pragma unroll
    for (int i = 0; i < 4; ++i) {
        int g = tid + i * 256;
        int ks = g >> 9, ms = (g >> 6) & 7, l = g & 63;
        srow[i] = ms * 16 + (l & 15);
        skof[i] = ks * 32 + (l >> 4) * 8;
    }

    f32x4 acc[4][4] = {};
    float4 ra[4][2], rb[4][2];

    // ---- prologue: load tile 0, stage into buf 0, issue tile-1 loads ----
#pragma unroll
    for (int i = 0; i < 4; ++i) {
        const float* sa = &X [(size_t)(rbase + srow[i]) * 512 + skof[i]];
        const float* sb = &W1[(size_t)(nbase + srow[i]) * 512 + skof[i]];
        ra[i][0] = *(const float4*)sa;  ra[i][1] = *(const float4*)(sa + 4);
        rb[i][0] = *(const float4*)sb;  rb[i][1] = *(const float4*)(sb + 4);
    }
#pragma unroll
    for (int i = 0; i < 4; ++i) {
        int g = tid + i * 256;
        union { __hip_bfloat162 q[4]; int4 pk; } ua, ub;
        ua.q[0] = __float22bfloat162_rn(make_float2(ra[i][0].x, ra[i][0].y));
        ua.q[1] = __float22bfloat162_rn(make_float2(ra[i][0].z, ra[i][0].w));
        ua.q[2] = __float22bfloat162_rn(make_float2(ra[i][1].x, ra[i][1].y));
        ua.q[3] = __float22bfloat162_rn(make_float2(ra[i][1].z, ra[i][1].w));
        ub.q[0] = __float22bfloat162_rn(make_float2(rb[i][0].x, rb[i][0].y));
        ub.q[1] = __float22bfloat162_rn(make_float2(rb[i][0].z, rb[i][0].w));
        ub.q[2] = __float22bfloat162_rn(make_float2(rb[i][1].x, rb[i][1].y));
        ub.q[3] = __float22bfloat162_rn(make_float2(rb[i][1].z, rb[i][1].w));
        *(int4*)&lds[0][g * 8]        = ua.pk;
        *(int4*)&lds[0][8192 + g * 8] = ub.pk;
    }
#pragma unroll
    for (int i = 0; i < 4; ++i) {
        const float* sa = &X [(size_t)(rbase + srow[i]) * 512 + 64 + skof[i]];
        const float* sb = &W1[(size_t)(nbase + srow[i]) * 512 + 64 + skof[i]];
        ra[i][0] = *(const float4*)sa;  ra[i][1] = *(const float4*)(sa + 4);
        rb[i][0] = *(const float4*)sb;  rb[i][1] = *(const float4*)(sb + 4);
    }

    int p = 0;
#pragma unroll
    for (int it = 0; it < 8; ++it) {
        // LDS-only barrier: own ds_writes complete, then sync; in-flight
        // global loads are NOT drained here.
        asm volatile("s_waitcnt lgkmcnt(0)\n\ts_barrier" ::: "memory");

        // ---- MFMA ks=0 from buf p ----
        {
            bf16x8 afr[4], bfr[4];
#pragma unroll
            for (int mf = 0; mf < 4; ++mf)
                afr[mf] = *(const bf16x8*)&lds[p][((wm * 4 + mf) * 64 + lane) * 8];
#pragma unroll
            for (int nf = 0; nf < 4; ++nf)
                bfr[nf] = *(const bf16x8*)&lds[p][8192 + ((wn * 4 + nf) * 64 + lane) * 8];
#pragma unroll
            for (int mf = 0; mf < 4; ++mf)
#pragma unroll
                for (int nf = 0; nf < 4; ++nf)
                    acc[mf][nf] = __builtin_amdgcn_mfma_f32_16x16x32_bf16(
                        afr[mf], bfr[nf], acc[mf][nf], 0, 0, 0);
        }

        // ---- stage tile it+1 into buf p^1 (overlaps MFMA); issue it+2 ----
        if (it < 7) {
#pragma unroll
            for (int i = 0; i < 4; ++i) {
                int g = tid + i * 256;
                union { __hip_bfloat162 q[4]; int4 pk; } ua, ub;
                ua.q[0] = __float22bfloat162_rn(make_float2(ra[i][0].x, ra[i][0].y));
                ua.q[1] = __float22bfloat162_rn(make_float2(ra[i][0].z, ra[i][0].w));
                ua.q[2] = __float22bfloat162_rn(make_float2(ra[i][1].x, ra[i][1].y));
                ua.q[3] = __float22bfloat162_rn(make_float2(ra[i][1].z, ra[i][1].w));
                ub.q[0] = __float22bfloat162_rn(make_float2(rb[i][0].x, rb[i][0].y));
                ub.q[1] = __float22bfloat162_rn(make_float2(rb[i][0].z, rb[i][0].w));
                ub.q[2] = __float22bfloat162_rn(make_float2(rb[i][1].x, rb[i][1].y));
                ub.q[3] = __float22bfloat162_rn(make_float2(rb[i][1].z, rb[i][1].w));
                *(int4*)&lds[p ^ 1][g * 8]        = ua.pk;
                *(int4*)&lds[p ^ 1][8192 + g * 8] = ub.pk;
            }
            if (it < 6) {
                const int kb2 = (it + 2) * 64;
#pragma unroll
                for (int i = 0; i < 4; ++i) {
                    const float* sa = &X [(size_t)(rbase + srow[i]) * 512 + kb2 + skof[i]];
                    const float* sb = &W1[(size_t)(nbase + srow[i]) * 512 + kb2 + skof[i]];
                    ra[i][0] = *(const float4*)sa;  ra[i][1] = *(const float4*)(sa + 4);
                    rb[i][0] = *(const float4*)sb;  rb[i][1] = *(const float4*)(sb + 4);
                }
            }
        }

        // ---- MFMA ks=1 from buf p ----
        {
            bf16x8 afr[4], bfr[4];
#pragma unroll
            for (int mf = 0; mf < 4; ++mf)
                afr[mf] = *(const bf16x8*)&lds[p][((8 + wm * 4 + mf) * 64 + lane) * 8];
#pragma unroll
            for (int nf = 0; nf < 4; ++nf)
                bfr[nf] = *(const bf16x8*)&lds[p][8192 + ((8 + wn * 4 + nf) * 64 + lane) * 8];
#pragma unroll
            for (int mf = 0; mf < 4; ++mf)
#pragma unroll
                for (int nf = 0; nf < 4; ++nf)
                    acc[mf][nf] = __builtin_amdgcn_mfma_f32_16x16x32_bf16(
                        afr[mf], bfr[nf], acc[mf][nf], 0, 0, 0);
        }

        p ^= 1;
    }

    float bc[4];
#pragma unroll
    for (int nf = 0; nf < 4; ++nf)
        bc[nf] = b1[nbase + wn * 64 + nf * 16 + (lane & 15)];
#pragma unroll
    for (int mf = 0; mf < 4; ++mf) {
#pragma unroll
        for (int nf = 0; nf < 4; ++nf) {
#pragma unroll
            for (int r = 0; r < 4; ++r) {
                int m = rbase + wm * 64 + mf * 16 + ((lane >> 4) << 2) + r;
                int n = nbase + wn * 64 + nf * 16 + (lane & 15);
                P[(size_t)m * 512 + n] = acc[mf][nf][r] + bc[nf];
            }
        }
    }
}

// ---------------------------------------------------------------------------
// Kernel 2: per-batch Gram via MFMA (unchanged — verified rounds 8-12)
// ---------------------------------------------------------------------------
__global__ __launch_bounds__(256) void gram_kernel(
    const float* __restrict__ X,    // [T][B][NX]
    float* __restrict__ Gt)         // [B][64][64]
{
    const int b    = blockIdx.x;
    const int tid  = threadIdx.x;
    const int lane = tid & 63;
    const int w    = tid >> 6;

    __shared__ unsigned short xs[4096 * 8];   // 64 KB, fragment order

#pragma unroll
    for (int i = 0; i < 16; ++i) {
        int g   = tid + i * 256;
        int ks  = g >> 8;
        int ms  = (g >> 6) & 3;
        int l   = g & 63;
        int row = ms * 16 + (l & 15);
        int k   = ks * 32 + (l >> 4) * 8;
        const float* src = &X[(size_t)row * (BATCH * NX) + (size_t)b * NX + k];
        float4 v0 = *(const float4*)src;
        float4 v1 = *(const float4*)(src + 4);
        union { __hip_bfloat162 q[4]; int4 pk; } u;
        u.q[0] = __float22bfloat162_rn(make_float2(v0.x, v0.y));
        u.q[1] = __float22bfloat162_rn(make_float2(v0.z, v0.w));
        u.q[2] = __float22bfloat162_rn(make_float2(v1.x, v1.y));
        u.q[3] = __float22bfloat162_rn(make_float2(v1.z, v1.w));
        *(int4*)&xs[g * 8] = u.pk;
    }
    __syncthreads();

    f32x4 acc[4] = {};
#pragma unroll
    for (int ks = 0; ks < 16; ++ks) {
        bf16x8 afr = *(const bf16x8*)&xs[((ks * 4 + w) * 64 + lane) * 8];
#pragma unroll
        for (int nf = 0; nf < 4; ++nf) {
            bf16x8 bfr = *(const bf16x8*)&xs[((ks * 4 + nf) * 64 + lane) * 8];
            acc[nf] = __builtin_amdgcn_mfma_f32_16x16x32_bf16(afr, bfr, acc[nf], 0, 0, 0);
        }
    }

#pragma unroll
    for (int nf = 0; nf < 4; ++nf) {
#pragma unroll
        for (int r = 0; r < 4; ++r) {
            int mrow = w * 16 + ((lane >> 4) << 2) + r;
            int ncol = nf * 16 + (lane & 15);
            Gt[((size_t)b * 64 + mrow) * 64 + ncol] = acc[nf][r];
        }
    }
}

// ---------------------------------------------------------------------------
// 64-lane sum via DPP; result valid in lane 63. (HW-verified rounds 4-12)
// ---------------------------------------------------------------------------
__device__ __forceinline__ float dpp_sum64(float v) {
    v += __int_as_float(__builtin_amdgcn_update_dpp(0, __float_as_int(v), 0x111, 0xf, 0xf, true)); // row_shr:1
    v += __int_as_float(__builtin_amdgcn_update_dpp(0, __float_as_int(v), 0x112, 0xf, 0xf, true)); // row_shr:2
    v += __int_as_float(__builtin_amdgcn_update_dpp(0, __float_as_int(v), 0x114, 0xf, 0xf, true)); // row_shr:4
    v += __int_as_float(__builtin_amdgcn_update_dpp(0, __float_as_int(v), 0x118, 0xf, 0xf, true)); // row_shr:8
    v += __int_as_float(__builtin_amdgcn_update_dpp(0, __float_as_int(v), 0x142, 0xf, 0xf, true)); // row_bcast:15
    v += __int_as_float(__builtin_amdgcn_update_dpp(0, __float_as_int(v), 0x143, 0xf, 0xf, true)); // row_bcast:31
    return v;
}

// ---------------------------------------------------------------------------
// Kernel 3: scan — round-12 version EXACTLY (best measured: 47.5 us).
// ---------------------------------------------------------------------------
__global__ __launch_bounds__(512, 1) void scan_kernel(
    const float* __restrict__ P,    // [T][B][NH]  (== outH, aliased)
    const float* __restrict__ Gt,   // [B][64][64]
    const float* __restrict__ w2,   // [NH][2]
    const float* __restrict__ b2,   // [2]
    const float* __restrict__ w21,  // [NH][2]
    const float* __restrict__ lamp,
    const float* __restrict__ etap,
    float* __restrict__ outH,       // [T][B][NH]
    float* __restrict__ outY)       // [T][B][2]
{
    const int b = blockIdx.x;
    const int h = threadIdx.x;

    __shared__ float Hs[64][512];   // 128 KB history; col h private to thread h
    __shared__ float C[16][64];     // per-chunk coefficient matrix
    __shared__ float lam_pow[64];
    __shared__ float red[2][16];

    const float eta = etap[0];
    const float lam = fminf(lamp[0], 1.0f);
    const float2 w21v = *(const float2*)&w21[2 * h];
    const float2 w2v  = *(const float2*)&w2[2 * h];
    const float b20 = b2[0], b21 = b2[1];
    const float* gb  = Gt + (size_t)b * 4096;
    const float* Pb  = P + (size_t)b * NH + h;
    float*       oHb = outH + (size_t)b * NH + h;

    if (h < 64)
        lam_pow[h] = (h == 0) ? 1.0f : exp2f((float)h * log2f(lam));
    __syncthreads();   // order lam_pow writes before chunk-0 C-build reads

#pragma unroll 1
    for (int c = 0; c < 4; ++c) {
        const int t0 = c * 16;

#pragma unroll
        for (int e = h; e < 1024; e += 512) {
            int tt = e >> 6, s = e & 63;
            int t  = t0 + tt;
            float cv = 0.f;
            if (s < t) cv = eta * lam_pow[t - 1 - s] * gb[t * 64 + s];
            C[tt][s] = cv;
        }

        float pvreg[16];
#pragma unroll
        for (int tt = 0; tt < 16; ++tt)
            pvreg[tt] = Pb[(size_t)(t0 + tt) * (BATCH * NH)];

        __syncthreads();   // C visible; also orders prev chunk's last red write

        float macc[16] = {};
        for (int s4 = 0; s4 < t0; s4 += 4) {
            float hsv0 = Hs[s4 + 0][h];
            float hsv1 = Hs[s4 + 1][h];
            float hsv2 = Hs[s4 + 2][h];
            float hsv3 = Hs[s4 + 3][h];
#pragma unroll
            for (int tt = 0; tt < 16; ++tt) {
                float4 cf = *(const float4*)&C[tt][s4];
                macc[tt] = fmaf(cf.x, hsv0, macc[tt]);
                macc[tt] = fmaf(cf.y, hsv1, macc[tt]);
                macc[tt] = fmaf(cf.z, hsv2, macc[tt]);
                macc[tt] = fmaf(cf.w, hsv3, macc[tt]);
            }
        }

        float hcur[16];
        float partial = pvreg[0] + macc[0];
#pragma unroll
        for (int tt = 0; tt < 16; ++tt) {
            const int t = t0 + tt;

            float a2x, a2y;
            if (t == 0) {
                a2x = 0.f; a2y = 0.f;
            } else {
                const int pr = (t - 1) & 1;
                float4 r0 = *(const float4*)&red[pr][0];
                float4 r1 = *(const float4*)&red[pr][4];
                float4 r2 = *(const float4*)&red[pr][8];
                float4 r3 = *(const float4*)&red[pr][12];
                float s0 = b20 + ((r0.x + r0.z) + (r1.x + r1.z)) + ((r2.x + r2.z) + (r3.x + r3.z));
                float s1 = b21 + ((r0.y + r0.w) + (r1.y + r1.w)) + ((r2.y + r2.w) + (r3.y + r3.w));
                a2x = s0; a2y = s1;
                if (h == 0) {
                    outY[((size_t)(t - 1) * BATCH + b) * 2 + 0] = 1.0f / (1.0f + __expf(-s0));
                    outY[((size_t)(t - 1) * BATCH + b) * 2 + 1] = 1.0f / (1.0f + __expf(-s1));
                }
            }

            float a1 = partial + w21v.x * a2x + w21v.y * a2y;
            float hv = 1.0f / (1.0f + __expf(-a1));
            hcur[tt] = hv;
            Hs[t][h] = hv;
            oHb[(size_t)t * (BATCH * NH)] = hv;

            float p0 = dpp_sum64(hv * w2v.x);
            float p1 = dpp_sum64(hv * w2v.y);
            if ((h & 63) == 63) {
                red[t & 1][(h >> 6) * 2]     = p0;
                red[t & 1][(h >> 6) * 2 + 1] = p1;
            }

            if (tt < 15) {
                partial = pvreg[tt + 1] + macc[tt + 1];
#pragma unroll
                for (int j = 0; j <= tt; ++j)
                    partial = fmaf(C[tt + 1][t0 + j], hcur[j], partial);
            }

            __syncthreads();
        }
    }

    {
        float4 r0 = *(const float4*)&red[63 & 1][0];
        float4 r1 = *(const float4*)&red[63 & 1][4];
        float4 r2 = *(const float4*)&red[63 & 1][8];
        float4 r3 = *(const float4*)&red[63 & 1][12];
        float s0 = b20 + ((r0.x + r0.z) + (r1.x + r1.z)) + ((r2.x + r2.z) + (r3.x + r3.z));
        float s1 = b21 + ((r0.y + r0.w) + (r1.y + r1.w)) + ((r2.y + r2.w) + (r3.y + r3.w));
        if (h == 0) {
            outY[((size_t)63 * BATCH + b) * 2 + 0] = 1.0f / (1.0f + __expf(-s0));
            outY[((size_t)63 * BATCH + b) * 2 + 1] = 1.0f / (1.0f + __expf(-s1));
        }
    }
}

// ---------------------------------------------------------------------------
extern "C" void kernel_launch(void* const* d_in, const int* in_sizes, int n_in,
                              void* d_out, int out_size, void* d_ws, size_t ws_size,
                              hipStream_t stream) {
    const float* x   = (const float*)d_in[0];
    const float* w1  = (const float*)d_in[1];
    const float* b1  = (const float*)d_in[2];
    const float* w2  = (const float*)d_in[3];
    const float* b2  = (const float*)d_in[4];
    const float* w21 = (const float*)d_in[5];
    const float* lam = (const float*)d_in[6];
    const float* eta = (const float*)d_in[7];

    float* outH = (float*)d_out;                       // [64*256*512], doubles as P
    float* outY = outH + (size_t)T_STEPS * BATCH * NH; // [64*256*2]
    float* Gt   = (float*)d_ws;                        // [256*64*64] = 4 MB

    gemm_bf16_kernel<<<dim3(128, 4), 256, 0, stream>>>(x, w1, b1, outH);
    gram_kernel<<<256, 256, 0, stream>>>(x, Gt);
    scan_kernel<<<256, 512, 0, stream>>>(outH, Gt, w2, b2, w21, lam, eta, outH, outY);
}